// Round 5
// baseline (137359.277 us; speedup 1.0000x reference)
//
#include <hip/hip_runtime.h>

#define T_STEPS 4096
#define HD 512
#define G3HD 1536
#define NCODES 4880
#define NWG 16
#define SENT 0xFFFFFFFFu

typedef __attribute__((ext_vector_type(2))) float v2f;
typedef __attribute__((ext_vector_type(4))) unsigned int v4u;

// ---------------------------------------------------------------------------
// GEMM1: visit[4096][512] = H^T (4096x4880) @ X_emb (4880x512)
// ---------------------------------------------------------------------------
__global__ __launch_bounds__(256) void gemm1_kernel(const float* __restrict__ H,
                                                    const float* __restrict__ X,
                                                    float* __restrict__ C) {
  __shared__ float As[16][68];
  __shared__ float Bs[16][68];
  const int m0 = blockIdx.x * 64;
  const int n0 = blockIdx.y * 64;
  const int tid = threadIdx.x;
  const int lk = tid >> 4;
  const int lm = (tid & 15) << 2;
  const int tm = (tid & 15) << 2;
  const int tn = (tid >> 4) << 2;
  float acc[4][4] = {};
  for (int k0 = 0; k0 < NCODES; k0 += 16) {
    float4 av = *(const float4*)(H + (size_t)(k0 + lk) * T_STEPS + m0 + lm);
    float4 bv = *(const float4*)(X + (size_t)(k0 + lk) * HD + n0 + lm);
    __syncthreads();
    *(float4*)(&As[lk][lm]) = av;
    *(float4*)(&Bs[lk][lm]) = bv;
    __syncthreads();
#pragma unroll
    for (int kk = 0; kk < 16; ++kk) {
      float4 a = *(const float4*)(&As[kk][tm]);
      float4 b = *(const float4*)(&Bs[kk][tn]);
      float ar[4] = {a.x, a.y, a.z, a.w};
      float br[4] = {b.x, b.y, b.z, b.w};
#pragma unroll
      for (int i = 0; i < 4; ++i)
#pragma unroll
        for (int j = 0; j < 4; ++j) acc[i][j] += ar[i] * br[j];
    }
  }
#pragma unroll
  for (int i = 0; i < 4; ++i) {
    float4 o = make_float4(acc[i][0], acc[i][1], acc[i][2], acc[i][3]);
    *(float4*)(C + (size_t)(m0 + tm + i) * HD + n0 + tn) = o;
  }
}

// ---------------------------------------------------------------------------
// GEMM2: gi[4096][1536] = visit (4096x512) @ W_ih^T (512x1536) + b_ih
// ---------------------------------------------------------------------------
__global__ __launch_bounds__(256) void gemm2_kernel(const float* __restrict__ A,
                                                    const float* __restrict__ B,
                                                    const float* __restrict__ bias,
                                                    float* __restrict__ Cout) {
  __shared__ float As[16][68];
  __shared__ float Bs[16][68];
  const int m0 = blockIdx.x * 64;
  const int n0 = blockIdx.y * 64;
  const int tid = threadIdx.x;
  const int lr = tid >> 2;
  const int lkq = (tid & 3) << 2;
  const int tm = (tid & 15) << 2;
  const int tn = (tid >> 4) << 2;
  float acc[4][4] = {};
  for (int k0 = 0; k0 < HD; k0 += 16) {
    float4 av = *(const float4*)(A + (size_t)(m0 + lr) * HD + k0 + lkq);
    float4 bv = *(const float4*)(B + (size_t)(n0 + lr) * HD + k0 + lkq);
    __syncthreads();
    As[lkq + 0][lr] = av.x; As[lkq + 1][lr] = av.y;
    As[lkq + 2][lr] = av.z; As[lkq + 3][lr] = av.w;
    Bs[lkq + 0][lr] = bv.x; Bs[lkq + 1][lr] = bv.y;
    Bs[lkq + 2][lr] = bv.z; Bs[lkq + 3][lr] = bv.w;
    __syncthreads();
#pragma unroll
    for (int kk = 0; kk < 16; ++kk) {
      float4 a = *(const float4*)(&As[kk][tm]);
      float4 b = *(const float4*)(&Bs[kk][tn]);
      float ar[4] = {a.x, a.y, a.z, a.w};
      float br[4] = {b.x, b.y, b.z, b.w};
#pragma unroll
      for (int i = 0; i < 4; ++i)
#pragma unroll
        for (int j = 0; j < 4; ++j) acc[i][j] += ar[i] * br[j];
    }
  }
  const float b0 = bias[n0 + tn + 0];
  const float b1 = bias[n0 + tn + 1];
  const float b2 = bias[n0 + tn + 2];
  const float b3 = bias[n0 + tn + 3];
#pragma unroll
  for (int i = 0; i < 4; ++i) {
    float4 o = make_float4(acc[i][0] + b0, acc[i][1] + b1, acc[i][2] + b2, acc[i][3] + b3);
    *(float4*)(Cout + (size_t)(m0 + tm + i) * G3HD + n0 + tn) = o;
  }
}

// ---------------------------------------------------------------------------
// Persistent GRU scan, XCD-pinned team, XCD-L2-level data-flow sync.
// 16 WGs x 512 thr (8 waves, 2/SIMD). rg = tid>>5 owns output elems
// j0=2rg, j1=2rg+1 of this WG's 32-elem slice and their 6 W_hh rows
// (3 gates x 2 elems), 16 k per lane (kc=tid&31) as float2 pairs pinned in
// VGPRs. Per step (ONE barrier):
//   wave0 polls full h[t-1] via global_load_dwordx4 sc0 (L1-bypass, served
//   by the shared XCD L2; sentinel 0xFFFFFFFF; sc0+sc1 fallback after 192
//   tries for guaranteed progress), scatters pairs to hT2; B1; all waves
//   pk_fma matvec + shfl_xor allreduce; lanes 0/1 of each rg compute gates
//   (native exp/rcp) and publish hnew via global_store sc0 (write-through
//   L1 -> L2). No flags, no fences, no second barrier (wave0's next scatter
//   is ordered after every rg's store by the data-flow itself).
// Logits are NOT computed here (off the critical path; see logits_kernel).
// ---------------------------------------------------------------------------
__global__ __launch_bounds__(512, 1) void scan_kernel(const float* __restrict__ gi,
                                                      const float* __restrict__ W_hh,
                                                      const float* __restrict__ b_hh,
                                                      float* __restrict__ hs,
                                                      int* __restrict__ ctrl) {
  __shared__ int s_role;
  const int tid = threadIdx.x;

  if (tid == 0) {
    int xcd;
    asm volatile("s_getreg_b32 %0, hwreg(HW_REG_XCC_ID)" : "=s"(xcd));
    int role = -1;
    const int slot = atomicAdd(&ctrl[xcd], 1);
    if (slot < NWG) {
      if (slot == NWG - 1) atomicCAS(&ctrl[8], -1, xcd);
      int wnr;
      while ((wnr = __hip_atomic_load(&ctrl[8], __ATOMIC_RELAXED,
                                      __HIP_MEMORY_SCOPE_AGENT)) < 0) {
        __builtin_amdgcn_s_sleep(16);
      }
      if (wnr == xcd) role = slot;
    }
    s_role = role;
  }
  __syncthreads();
  const int g = s_role;
  if (g < 0) return;

  const int rg = tid >> 5;   // 0..15: owns local elems j0=2rg, j1=2rg+1
  const int kc = tid & 31;   // k-chunk: 16 k (8 pairs) per lane

  // 6 rows: r=0..2 -> gates r/z/n of j0; r=3..5 -> gates of j1
  v2f w2[6][8];
#pragma unroll
  for (int r = 0; r < 6; ++r) {
    const int jl = 2 * rg + (r >= 3);
    const int grow = (r % 3) * HD + g * 32 + jl;
    const v2f* wv = (const v2f*)(W_hh + (size_t)grow * HD + kc * 16);
#pragma unroll
    for (int m = 0; m < 8; ++m) w2[r][m] = wv[m];
  }
  // pin W in VGPRs: opaque defs the compiler cannot rematerialize
#pragma unroll
  for (int r = 0; r < 6; ++r)
    asm volatile("" : "+v"(w2[r][0]), "+v"(w2[r][1]), "+v"(w2[r][2]), "+v"(w2[r][3]),
                      "+v"(w2[r][4]), "+v"(w2[r][5]), "+v"(w2[r][6]), "+v"(w2[r][7]));

  // gate-lane constants (lanes kc<2 of each rg)
  float bh0 = 0.f, bh1 = 0.f, bh2 = 0.f;
  int jloc = 2 * rg + kc;  // valid for kc<2
  if (kc < 2) {
    bh0 = b_hh[0 * HD + g * 32 + jloc];
    bh1 = b_hh[1 * HD + g * 32 + jloc];
    bh2 = b_hh[2 * HD + g * 32 + jloc];
  }

  // hT2 pair layout: h[k], k = kc*16 + 2m  at  hT2[m*32 + kc]
  __shared__ v2f hT2[256];

  unsigned int* hs_u = (unsigned int*)hs;

  // gi prefetch registers (gate lanes only), loaded one step ahead
  float gir = 0.f, giz = 0.f, gin = 0.f;
  if (kc < 2) {
    const float* gp = gi + g * 32 + jloc;
    gir = gp[0];
    giz = gp[HD];
    gin = gp[2 * HD];
  }

  for (int t = 0; t < T_STEPS; ++t) {
    if (tid < 64) {
      if (t == 0) {
        const v2f z2 = (v2f)(0.f);
#pragma unroll
        for (int m = 0; m < 4; ++m) hT2[((tid & 1) * 4 + m) * 32 + (tid >> 1)] = z2;
      } else {
        const unsigned int* p = hs_u + (size_t)(t - 1) * HD + tid * 8;
        v4u a, b;
        int tries = 0;
        for (;;) {
          if (tries < 192) {
            asm volatile("global_load_dwordx4 %0, %2, off sc0\n\t"
                         "global_load_dwordx4 %1, %2, off offset:16 sc0\n\t"
                         "s_waitcnt vmcnt(0)"
                         : "=v"(a), "=v"(b)
                         : "v"(p)
                         : "memory");
          } else {  // progress guarantee: device-scope (bypass L1+L2)
            asm volatile("global_load_dwordx4 %0, %2, off sc0 sc1\n\t"
                         "global_load_dwordx4 %1, %2, off offset:16 sc0 sc1\n\t"
                         "s_waitcnt vmcnt(0)"
                         : "=v"(a), "=v"(b)
                         : "v"(p)
                         : "memory");
          }
          if (a.x != SENT && a.y != SENT && a.z != SENT && a.w != SENT &&
              b.x != SENT && b.y != SENT && b.z != SENT && b.w != SENT)
            break;
          ++tries;
        }
        v2f p0, p1, p2, p3;
        p0.x = __uint_as_float(a.x); p0.y = __uint_as_float(a.y);
        p1.x = __uint_as_float(a.z); p1.y = __uint_as_float(a.w);
        p2.x = __uint_as_float(b.x); p2.y = __uint_as_float(b.y);
        p3.x = __uint_as_float(b.z); p3.y = __uint_as_float(b.w);
        const int base = (tid & 1) * 4;
        const int col = tid >> 1;
        hT2[(base + 0) * 32 + col] = p0;
        hT2[(base + 1) * 32 + col] = p1;
        hT2[(base + 2) * 32 + col] = p2;
        hT2[(base + 3) * 32 + col] = p3;
      }
    }
    __syncthreads();  // B1: hT2 = h[t-1] ready (the ONLY barrier per step)

    // prefetch next step's gi (consumed next iteration; hidden behind matvec)
    float gir_n = gir, giz_n = giz, gin_n = gin;
    if (kc < 2 && t + 1 < T_STEPS) {
      const float* gp = gi + (size_t)(t + 1) * G3HD + g * 32 + jloc;
      gir_n = gp[0];
      giz_n = gp[HD];
      gin_n = gp[2 * HD];
    }

    v2f acc[6];
#pragma unroll
    for (int r = 0; r < 6; ++r) acc[r] = (v2f)(0.f);
#pragma unroll
    for (int m = 0; m < 8; ++m) {
      const v2f hv = hT2[m * 32 + kc];
#pragma unroll
      for (int r = 0; r < 6; ++r) acc[r] = __builtin_elementwise_fma(w2[r][m], hv, acc[r]);
    }
    float s[6];
#pragma unroll
    for (int r = 0; r < 6; ++r) s[r] = acc[r].x + acc[r].y;
#pragma unroll
    for (int mask = 1; mask <= 16; mask <<= 1) {
#pragma unroll
      for (int r = 0; r < 6; ++r) s[r] += __shfl_xor(s[r], mask);
    }

    if (kc < 2) {
      const float sr = ((kc == 0) ? s[0] : s[3]) + bh0;
      const float sz = ((kc == 0) ? s[1] : s[4]) + bh1;
      const float sn = ((kc == 0) ? s[2] : s[5]) + bh2;
      const float r = __builtin_amdgcn_rcpf(1.f + __expf(-(gir + sr)));
      const float z = __builtin_amdgcn_rcpf(1.f + __expf(-(giz + sz)));
      const float y = gin + r * sn;
      const float n = 1.f - 2.f * __builtin_amdgcn_rcpf(__expf(2.f * y) + 1.f);
      const int kg = g * 32 + jloc;
      const float hprev = ((const float*)hT2)[((kg & 15) >> 1) * 64 + (kg >> 4) * 2 + (kg & 1)];
      const float hnew = n + z * (hprev - n);
      unsigned int* pst = hs_u + (size_t)t * HD + kg;
      const unsigned int uval = __float_as_uint(hnew);
      asm volatile("global_store_dword %0, %1, off sc0" ::"v"(pst), "v"(uval) : "memory");
    }
    gir = gir_n; giz = giz_n; gin = gin_n;
  }
}

// ---------------------------------------------------------------------------
// logits[t] = dot(hs[t], w_att).  64 WGs x 4 waves; one wave per t-row.
// ---------------------------------------------------------------------------
__global__ __launch_bounds__(256) void logits_kernel(const float* __restrict__ hs,
                                                     const float* __restrict__ w_att,
                                                     float* __restrict__ logits) {
  const int lane = threadIdx.x & 63;
  const int wv = threadIdx.x >> 6;  // 0..3
  float4 wa0 = *(const float4*)(w_att + lane * 8);
  float4 wa1 = *(const float4*)(w_att + lane * 8 + 4);
  const int t0 = blockIdx.x * 64 + wv * 16;
  for (int i = 0; i < 16; ++i) {
    const int t = t0 + i;
    const float* hp = hs + (size_t)t * HD + lane * 8;
    float4 h0 = *(const float4*)hp;
    float4 h1 = *(const float4*)(hp + 4);
    float s = h0.x * wa0.x + h0.y * wa0.y + h0.z * wa0.z + h0.w * wa0.w +
              h1.x * wa1.x + h1.y * wa1.y + h1.z * wa1.z + h1.w * wa1.w;
#pragma unroll
    for (int o = 1; o <= 32; o <<= 1) s += __shfl_xor(s, o);
    if (lane == 0) logits[t] = s;
  }
}

// ---------------------------------------------------------------------------
// Softmax over 4096 logits, write alpha; zero out.
// ---------------------------------------------------------------------------
__global__ __launch_bounds__(256) void softmax_kernel(const float* __restrict__ logits,
                                                      float* __restrict__ alpha,
                                                      float* __restrict__ out) {
  __shared__ float tmp[4];
  const int tid = threadIdx.x;
  float l[16];
  float m = -1e30f;
#pragma unroll
  for (int i = 0; i < 16; ++i) {
    l[i] = logits[i * 256 + tid];
    m = fmaxf(m, l[i]);
  }
#pragma unroll
  for (int o = 32; o > 0; o >>= 1) m = fmaxf(m, __shfl_xor(m, o));
  if ((tid & 63) == 0) tmp[tid >> 6] = m;
  __syncthreads();
  m = fmaxf(fmaxf(tmp[0], tmp[1]), fmaxf(tmp[2], tmp[3]));
  __syncthreads();
  float e[16];
  float s = 0.f;
#pragma unroll
  for (int i = 0; i < 16; ++i) {
    e[i] = expf(l[i] - m);
    s += e[i];
  }
#pragma unroll
  for (int o = 32; o > 0; o >>= 1) s += __shfl_xor(s, o);
  if ((tid & 63) == 0) tmp[tid >> 6] = s;
  __syncthreads();
  s = tmp[0] + tmp[1] + tmp[2] + tmp[3];
  const float inv = 1.f / s;
#pragma unroll
  for (int i = 0; i < 16; ++i) alpha[i * 256 + tid] = e[i] * inv;
  out[tid] = 0.f;
  out[256 + tid] = 0.f;
}

// ---------------------------------------------------------------------------
// out[j] = sum_t alpha[t] * hs[t][j].  128 WGs: 2 j-halves x 64 t-chunks.
// ---------------------------------------------------------------------------
__global__ __launch_bounds__(256) void wsum_kernel(const float* __restrict__ alpha,
                                                   const float* __restrict__ hs,
                                                   float* __restrict__ out) {
  const int tid = threadIdx.x;
  const int jblk = (blockIdx.x & 1) * 256;
  const int tc = blockIdx.x >> 1;
  float acc = 0.f;
  for (int tt = 0; tt < 64; ++tt) {
    const int t = tc * 64 + tt;
    acc += alpha[t] * hs[(size_t)t * HD + jblk + tid];
  }
  atomicAdd(&out[jblk + tid], acc);
}

extern "C" void kernel_launch(void* const* d_in, const int* in_sizes, int n_in,
                              void* d_out, int out_size, void* d_ws, size_t ws_size,
                              hipStream_t stream) {
  const float* H     = (const float*)d_in[0];
  // d_in[1] = TE, unused by the reference
  const float* X_emb = (const float*)d_in[2];
  const float* W_ih  = (const float*)d_in[3];
  const float* W_hh  = (const float*)d_in[4];
  const float* b_ih  = (const float*)d_in[5];
  const float* b_hh  = (const float*)d_in[6];
  const float* w_att = (const float*)d_in[7];
  float* out = (float*)d_out;

  char* ws = (char*)d_ws;
  float* visit  = (float*)(ws + 0);          //  8 MB: 4096x512
  float* gi     = (float*)(ws + 8388608);    // 25 MB: 4096x1536
  float* hs     = (float*)(ws + 33554432);   //  8 MB: 4096x512
  float* logits = (float*)(ws + 41943040);   // 16 KB: 4096
  float* alpha  = (float*)(ws + 42205184);   // 16 KB
  int*   ctrl   = (int*)(ws + 42221568);     // [0..7] per-XCD counters, [8] winner

  // sentinel-fill hs (0xFFFFFFFF = -NaN, unreachable from finite GRU math)
  hipMemsetAsync(hs, 0xFF, (size_t)T_STEPS * HD * sizeof(float), stream);
  hipMemsetAsync(ctrl, 0, 8 * sizeof(int), stream);
  hipMemsetAsync(ctrl + 8, 0xFF, sizeof(int), stream);  // winner = -1

  gemm1_kernel<<<dim3(64, 8), 256, 0, stream>>>(H, X_emb, visit);
  gemm2_kernel<<<dim3(64, 24), 256, 0, stream>>>(visit, W_ih, b_ih, gi);
  scan_kernel<<<256, 512, 0, stream>>>(gi, W_hh, b_hh, hs, ctrl);
  logits_kernel<<<64, 256, 0, stream>>>(hs, w_att, logits);
  softmax_kernel<<<1, 256, 0, stream>>>(logits, alpha, out);
  wsum_kernel<<<128, 256, 0, stream>>>(alpha, hs, out);
}

// Round 6
// 11416.523 us; speedup vs baseline: 12.0316x; 12.0316x over previous
//
#include <hip/hip_runtime.h>

#define T_STEPS 4096
#define HD 512
#define G3HD 1536
#define NCODES 4880
#define NWG 16
#define SENT 0xFFFFFFFFu

typedef __attribute__((ext_vector_type(2))) float v2f;

// ---------------------------------------------------------------------------
// GEMM1: visit[4096][512] = H^T (4096x4880) @ X_emb (4880x512)
// ---------------------------------------------------------------------------
__global__ __launch_bounds__(256) void gemm1_kernel(const float* __restrict__ H,
                                                    const float* __restrict__ X,
                                                    float* __restrict__ C) {
  __shared__ float As[16][68];
  __shared__ float Bs[16][68];
  const int m0 = blockIdx.x * 64;
  const int n0 = blockIdx.y * 64;
  const int tid = threadIdx.x;
  const int lk = tid >> 4;
  const int lm = (tid & 15) << 2;
  const int tm = (tid & 15) << 2;
  const int tn = (tid >> 4) << 2;
  float acc[4][4] = {};
  for (int k0 = 0; k0 < NCODES; k0 += 16) {
    float4 av = *(const float4*)(H + (size_t)(k0 + lk) * T_STEPS + m0 + lm);
    float4 bv = *(const float4*)(X + (size_t)(k0 + lk) * HD + n0 + lm);
    __syncthreads();
    *(float4*)(&As[lk][lm]) = av;
    *(float4*)(&Bs[lk][lm]) = bv;
    __syncthreads();
#pragma unroll
    for (int kk = 0; kk < 16; ++kk) {
      float4 a = *(const float4*)(&As[kk][tm]);
      float4 b = *(const float4*)(&Bs[kk][tn]);
      float ar[4] = {a.x, a.y, a.z, a.w};
      float br[4] = {b.x, b.y, b.z, b.w};
#pragma unroll
      for (int i = 0; i < 4; ++i)
#pragma unroll
        for (int j = 0; j < 4; ++j) acc[i][j] += ar[i] * br[j];
    }
  }
#pragma unroll
  for (int i = 0; i < 4; ++i) {
    float4 o = make_float4(acc[i][0], acc[i][1], acc[i][2], acc[i][3]);
    *(float4*)(C + (size_t)(m0 + tm + i) * HD + n0 + tn) = o;
  }
}

// ---------------------------------------------------------------------------
// GEMM2: gi[4096][1536] = visit (4096x512) @ W_ih^T (512x1536) + b_ih
// ---------------------------------------------------------------------------
__global__ __launch_bounds__(256) void gemm2_kernel(const float* __restrict__ A,
                                                    const float* __restrict__ B,
                                                    const float* __restrict__ bias,
                                                    float* __restrict__ Cout) {
  __shared__ float As[16][68];
  __shared__ float Bs[16][68];
  const int m0 = blockIdx.x * 64;
  const int n0 = blockIdx.y * 64;
  const int tid = threadIdx.x;
  const int lr = tid >> 2;
  const int lkq = (tid & 3) << 2;
  const int tm = (tid & 15) << 2;
  const int tn = (tid >> 4) << 2;
  float acc[4][4] = {};
  for (int k0 = 0; k0 < HD; k0 += 16) {
    float4 av = *(const float4*)(A + (size_t)(m0 + lr) * HD + k0 + lkq);
    float4 bv = *(const float4*)(B + (size_t)(n0 + lr) * HD + k0 + lkq);
    __syncthreads();
    As[lkq + 0][lr] = av.x; As[lkq + 1][lr] = av.y;
    As[lkq + 2][lr] = av.z; As[lkq + 3][lr] = av.w;
    Bs[lkq + 0][lr] = bv.x; Bs[lkq + 1][lr] = bv.y;
    Bs[lkq + 2][lr] = bv.z; Bs[lkq + 3][lr] = bv.w;
    __syncthreads();
#pragma unroll
    for (int kk = 0; kk < 16; ++kk) {
      float4 a = *(const float4*)(&As[kk][tm]);
      float4 b = *(const float4*)(&Bs[kk][tn]);
      float ar[4] = {a.x, a.y, a.z, a.w};
      float br[4] = {b.x, b.y, b.z, b.w};
#pragma unroll
      for (int i = 0; i < 4; ++i)
#pragma unroll
        for (int j = 0; j < 4; ++j) acc[i][j] += ar[i] * br[j];
    }
  }
  const float b0 = bias[n0 + tn + 0];
  const float b1 = bias[n0 + tn + 1];
  const float b2 = bias[n0 + tn + 2];
  const float b3 = bias[n0 + tn + 3];
#pragma unroll
  for (int i = 0; i < 4; ++i) {
    float4 o = make_float4(acc[i][0] + b0, acc[i][1] + b1, acc[i][2] + b2, acc[i][3] + b3);
    *(float4*)(Cout + (size_t)(m0 + tm + i) * G3HD + n0 + tn) = o;
  }
}

// ---------------------------------------------------------------------------
// Persistent GRU scan, XCD-pinned team, ladder-scoped data-flow sync.
// 16 WGs x 512 thr (8 waves). rg=tid>>5 owns output elems 2rg,2rg+1 and their
// 6 W_hh rows (float2 pairs, AGPR-backed). Per step (ONE barrier):
//   wave0 polls h[t-1]: plain loads (may hit L1/L2) -> on sentinel, acquire-
//   agent fence (buffer_inv: drops stale L1) -> retry; after 64 rounds the
//   wave permanently switches to AGENT-scope loads (R4-proven MALL path).
//   Scatter to hT2; barrier; pk_fma matvec + shfl_xor allreduce; gate lanes
//   (kc<2 of each rg) compute gates (native exp/rcp) and publish hnew via
//   relaxed AGENT store (R4-proven visibility). Single barrier is race-free:
//   wave0 can only pass its poll at t+1 after every wave of every WG stored
//   its gate outputs at t, which (wave lockstep + shfl) implies all hT2 reads
//   of step t are complete.
// ---------------------------------------------------------------------------
__global__ __launch_bounds__(512, 1) void scan_kernel(const float* __restrict__ gi,
                                                      const float* __restrict__ W_hh,
                                                      const float* __restrict__ b_hh,
                                                      float* __restrict__ hs,
                                                      int* __restrict__ ctrl) {
  __shared__ int s_role;
  const int tid = threadIdx.x;

  if (tid == 0) {
    int xcd;
    asm volatile("s_getreg_b32 %0, hwreg(HW_REG_XCC_ID)" : "=s"(xcd));
    int role = -1;
    const int slot = atomicAdd(&ctrl[xcd], 1);
    if (slot < NWG) {
      if (slot == NWG - 1) atomicCAS(&ctrl[8], -1, xcd);
      int wnr;
      while ((wnr = __hip_atomic_load(&ctrl[8], __ATOMIC_RELAXED,
                                      __HIP_MEMORY_SCOPE_AGENT)) < 0) {
        __builtin_amdgcn_s_sleep(16);
      }
      if (wnr == xcd) role = slot;
    }
    s_role = role;
  }
  __syncthreads();
  const int g = s_role;
  if (g < 0) return;

  const int rg = tid >> 5;   // 0..15: owns local elems j0=2rg, j1=2rg+1
  const int kc = tid & 31;   // k-chunk: 16 k (8 pairs) per lane

  // 6 rows: r=0..2 -> gates r/z/n of j0; r=3..5 -> gates of j1
  v2f w2[6][8];
#pragma unroll
  for (int r = 0; r < 6; ++r) {
    const int jl = 2 * rg + (r >= 3);
    const int grow = (r % 3) * HD + g * 32 + jl;
    const v2f* wv = (const v2f*)(W_hh + (size_t)grow * HD + kc * 16);
#pragma unroll
    for (int m = 0; m < 8; ++m) w2[r][m] = wv[m];
  }

  // gate-lane constants (lanes kc<2 of each rg)
  float bh0 = 0.f, bh1 = 0.f, bh2 = 0.f;
  const int jloc = 2 * rg + kc;  // valid for kc<2
  if (kc < 2) {
    bh0 = b_hh[0 * HD + g * 32 + jloc];
    bh1 = b_hh[1 * HD + g * 32 + jloc];
    bh2 = b_hh[2 * HD + g * 32 + jloc];
  }

  // hT2 pair layout: h[k], k = kc*16 + 2m  at  hT2[m*32 + kc]
  __shared__ v2f hT2[256];

  unsigned int* hs_u = (unsigned int*)hs;

  // gi prefetch registers (gate lanes only), loaded one step ahead
  float gir = 0.f, giz = 0.f, gin = 0.f;
  if (kc < 2) {
    const float* gp = gi + g * 32 + jloc;
    gir = gp[0];
    giz = gp[HD];
    gin = gp[2 * HD];
  }

  bool use_agent = false;  // sticky per-wave fallback mode (wave0 only)

  for (int t = 0; t < T_STEPS; ++t) {
    if (tid < 64) {
      if (t == 0) {
        const v2f z2 = (v2f)(0.f);
#pragma unroll
        for (int m = 0; m < 4; ++m) hT2[((tid & 1) * 4 + m) * 32 + (tid >> 1)] = z2;
      } else {
        const unsigned long long* p64 =
            (const unsigned long long*)(hs_u + (size_t)(t - 1) * HD + tid * 8);
        unsigned long long u[4];
        int rounds = 0;
        for (;;) {
          bool ok = true;
          if (!use_agent) {
#pragma unroll
            for (int m = 0; m < 4; ++m)
              u[m] = __hip_atomic_load(p64 + m, __ATOMIC_RELAXED,
                                       __HIP_MEMORY_SCOPE_WORKGROUP);
          } else {
#pragma unroll
            for (int m = 0; m < 4; ++m)
              u[m] = __hip_atomic_load(p64 + m, __ATOMIC_RELAXED,
                                       __HIP_MEMORY_SCOPE_AGENT);
          }
#pragma unroll
          for (int m = 0; m < 4; ++m)
            ok &= ((unsigned int)u[m] != SENT) & ((unsigned int)(u[m] >> 32) != SENT);
          if (ok) break;
          if (!use_agent) {
            // drop stale L1 lines; next plain load hits L2 (or misses to MALL)
            __builtin_amdgcn_fence(__ATOMIC_ACQUIRE, "agent");
            if (++rounds >= 64) use_agent = true;  // sticky MALL fallback
          }
        }
        v2f p0, p1, p2, p3;
        p0.x = __uint_as_float((unsigned int)u[0]);
        p0.y = __uint_as_float((unsigned int)(u[0] >> 32));
        p1.x = __uint_as_float((unsigned int)u[1]);
        p1.y = __uint_as_float((unsigned int)(u[1] >> 32));
        p2.x = __uint_as_float((unsigned int)u[2]);
        p2.y = __uint_as_float((unsigned int)(u[2] >> 32));
        p3.x = __uint_as_float((unsigned int)u[3]);
        p3.y = __uint_as_float((unsigned int)(u[3] >> 32));
        const int base = (tid & 1) * 4;
        const int col = tid >> 1;
        hT2[(base + 0) * 32 + col] = p0;
        hT2[(base + 1) * 32 + col] = p1;
        hT2[(base + 2) * 32 + col] = p2;
        hT2[(base + 3) * 32 + col] = p3;
      }
    }
    __syncthreads();  // B1: hT2 = h[t-1] ready (the ONLY barrier per step)

    // prefetch next step's gi (consumed next iteration; hidden behind matvec)
    float gir_n = gir, giz_n = giz, gin_n = gin;
    if (kc < 2 && t + 1 < T_STEPS) {
      const float* gp = gi + (size_t)(t + 1) * G3HD + g * 32 + jloc;
      gir_n = gp[0];
      giz_n = gp[HD];
      gin_n = gp[2 * HD];
    }

    v2f acc[6];
#pragma unroll
    for (int r = 0; r < 6; ++r) acc[r] = (v2f)(0.f);
#pragma unroll
    for (int m = 0; m < 8; ++m) {
      const v2f hv = hT2[m * 32 + kc];
#pragma unroll
      for (int r = 0; r < 6; ++r) acc[r] = __builtin_elementwise_fma(w2[r][m], hv, acc[r]);
    }
    float s[6];
#pragma unroll
    for (int r = 0; r < 6; ++r) s[r] = acc[r].x + acc[r].y;
#pragma unroll
    for (int mask = 1; mask <= 16; mask <<= 1) {
#pragma unroll
      for (int r = 0; r < 6; ++r) s[r] += __shfl_xor(s[r], mask);
    }

    if (kc < 2) {
      const float sr = ((kc == 0) ? s[0] : s[3]) + bh0;
      const float sz = ((kc == 0) ? s[1] : s[4]) + bh1;
      const float sn = ((kc == 0) ? s[2] : s[5]) + bh2;
      const float r = __builtin_amdgcn_rcpf(1.f + __expf(-(gir + sr)));
      const float z = __builtin_amdgcn_rcpf(1.f + __expf(-(giz + sz)));
      const float y = gin + r * sn;
      const float n = 1.f - 2.f * __builtin_amdgcn_rcpf(__expf(2.f * y) + 1.f);
      const int kg = g * 32 + jloc;
      const float hprev = ((const float*)hT2)[((kg & 15) >> 1) * 64 + (kg >> 4) * 2 + (kg & 1)];
      const float hnew = n + z * (hprev - n);
      __hip_atomic_store(hs_u + (size_t)t * HD + kg, __float_as_uint(hnew),
                         __ATOMIC_RELAXED, __HIP_MEMORY_SCOPE_AGENT);
    }
    gir = gir_n; giz = giz_n; gin = gin_n;
  }
}

// ---------------------------------------------------------------------------
// logits[t] = dot(hs[t], w_att).  64 WGs x 4 waves; one wave per 16 t-rows.
// ---------------------------------------------------------------------------
__global__ __launch_bounds__(256) void logits_kernel(const float* __restrict__ hs,
                                                     const float* __restrict__ w_att,
                                                     float* __restrict__ logits) {
  const int lane = threadIdx.x & 63;
  const int wv = threadIdx.x >> 6;  // 0..3
  float4 wa0 = *(const float4*)(w_att + lane * 8);
  float4 wa1 = *(const float4*)(w_att + lane * 8 + 4);
  const int t0 = blockIdx.x * 64 + wv * 16;
  for (int i = 0; i < 16; ++i) {
    const int t = t0 + i;
    const float* hp = hs + (size_t)t * HD + lane * 8;
    float4 h0 = *(const float4*)hp;
    float4 h1 = *(const float4*)(hp + 4);
    float s = h0.x * wa0.x + h0.y * wa0.y + h0.z * wa0.z + h0.w * wa0.w +
              h1.x * wa1.x + h1.y * wa1.y + h1.z * wa1.z + h1.w * wa1.w;
#pragma unroll
    for (int o = 1; o <= 32; o <<= 1) s += __shfl_xor(s, o);
    if (lane == 0) logits[t] = s;
  }
}

// ---------------------------------------------------------------------------
// Softmax over 4096 logits, write alpha; zero out.
// ---------------------------------------------------------------------------
__global__ __launch_bounds__(256) void softmax_kernel(const float* __restrict__ logits,
                                                      float* __restrict__ alpha,
                                                      float* __restrict__ out) {
  __shared__ float tmp[4];
  const int tid = threadIdx.x;
  float l[16];
  float m = -1e30f;
#pragma unroll
  for (int i = 0; i < 16; ++i) {
    l[i] = logits[i * 256 + tid];
    m = fmaxf(m, l[i]);
  }
#pragma unroll
  for (int o = 32; o > 0; o >>= 1) m = fmaxf(m, __shfl_xor(m, o));
  if ((tid & 63) == 0) tmp[tid >> 6] = m;
  __syncthreads();
  m = fmaxf(fmaxf(tmp[0], tmp[1]), fmaxf(tmp[2], tmp[3]));
  __syncthreads();
  float e[16];
  float s = 0.f;
#pragma unroll
  for (int i = 0; i < 16; ++i) {
    e[i] = expf(l[i] - m);
    s += e[i];
  }
#pragma unroll
  for (int o = 32; o > 0; o >>= 1) s += __shfl_xor(s, o);
  if ((tid & 63) == 0) tmp[tid >> 6] = s;
  __syncthreads();
  s = tmp[0] + tmp[1] + tmp[2] + tmp[3];
  const float inv = 1.f / s;
#pragma unroll
  for (int i = 0; i < 16; ++i) alpha[i * 256 + tid] = e[i] * inv;
  out[tid] = 0.f;
  out[256 + tid] = 0.f;
}

// ---------------------------------------------------------------------------
// out[j] = sum_t alpha[t] * hs[t][j].  128 WGs: 2 j-halves x 64 t-chunks.
// ---------------------------------------------------------------------------
__global__ __launch_bounds__(256) void wsum_kernel(const float* __restrict__ alpha,
                                                   const float* __restrict__ hs,
                                                   float* __restrict__ out) {
  const int tid = threadIdx.x;
  const int jblk = (blockIdx.x & 1) * 256;
  const int tc = blockIdx.x >> 1;
  float acc = 0.f;
  for (int tt = 0; tt < 64; ++tt) {
    const int t = tc * 64 + tt;
    acc += alpha[t] * hs[(size_t)t * HD + jblk + tid];
  }
  atomicAdd(&out[jblk + tid], acc);
}

extern "C" void kernel_launch(void* const* d_in, const int* in_sizes, int n_in,
                              void* d_out, int out_size, void* d_ws, size_t ws_size,
                              hipStream_t stream) {
  const float* H     = (const float*)d_in[0];
  // d_in[1] = TE, unused by the reference
  const float* X_emb = (const float*)d_in[2];
  const float* W_ih  = (const float*)d_in[3];
  const float* W_hh  = (const float*)d_in[4];
  const float* b_ih  = (const float*)d_in[5];
  const float* b_hh  = (const float*)d_in[6];
  const float* w_att = (const float*)d_in[7];
  float* out = (float*)d_out;

  char* ws = (char*)d_ws;
  float* visit  = (float*)(ws + 0);          //  8 MB: 4096x512
  float* gi     = (float*)(ws + 8388608);    // 25 MB: 4096x1536
  float* hs     = (float*)(ws + 33554432);   //  8 MB: 4096x512
  float* logits = (float*)(ws + 41943040);   // 16 KB: 4096
  float* alpha  = (float*)(ws + 42205184);   // 16 KB
  int*   ctrl   = (int*)(ws + 42221568);     // [0..7] per-XCD counters, [8] winner

  // sentinel-fill hs (0xFFFFFFFF = -NaN, unreachable from finite GRU math)
  hipMemsetAsync(hs, 0xFF, (size_t)T_STEPS * HD * sizeof(float), stream);
  hipMemsetAsync(ctrl, 0, 8 * sizeof(int), stream);
  hipMemsetAsync(ctrl + 8, 0xFF, sizeof(int), stream);  // winner = -1

  gemm1_kernel<<<dim3(64, 8), 256, 0, stream>>>(H, X_emb, visit);
  gemm2_kernel<<<dim3(64, 24), 256, 0, stream>>>(visit, W_ih, b_ih, gi);
  scan_kernel<<<256, 512, 0, stream>>>(gi, W_hh, b_hh, hs, ctrl);
  logits_kernel<<<64, 256, 0, stream>>>(hs, w_att, logits);
  softmax_kernel<<<1, 256, 0, stream>>>(logits, alpha, out);
  wsum_kernel<<<128, 256, 0, stream>>>(alpha, hs, out);
}